// Round 12
// baseline (161.061 us; speedup 1.0000x reference)
//
#include <hip/hip_runtime.h>
#include <math.h>

// Round 20: r19 (session-best 150.1us) + dense barrier-bubble filling.
// fused_dense was 256 blocks = exactly 1 block/CU -> its 8-barrier chain is
// fully exposed (same disease as r11-r15's fused kernels). Now 512 blocks:
// 2 per batch, both compute the identical deterministic dense pipeline for
// their batch (duplicated ~2.1 GFLOP of MFMA - trivial), each writes a
// DISJOINT half of the output rows. 2 blocks/CU co-resident (LDS 48KBx2,
// VGPR 128x16 waves) -> barrier bubbles of one block filled by the other.
// conv_all/pack_all byte-identical to r19.

typedef __attribute__((ext_vector_type(8))) short bf16x8;
typedef __attribute__((ext_vector_type(4))) float f32x4;

__device__ __forceinline__ short f2bf(float f) {
  union { float f; unsigned u; } v; v.f = f;
  unsigned r = v.u + 0x7fffu + ((v.u >> 16) & 1u);
  return (short)(r >> 16);
}
__device__ __forceinline__ float bf2f(unsigned short u) {
  union { unsigned u; float f; } v; v.u = ((unsigned)u) << 16;
  return v.f;
}

// ---------- all weight packs (fragment order for convs) — unchanged ----------
__global__ __launch_bounds__(256) void pack_all(
    const float* __restrict__ w_c1, const float* __restrict__ w_c2,
    const float* __restrict__ w_c3, const float* __restrict__ w_fc,
    const float* __restrict__ w_g1, const float* __restrict__ w_g2,
    short* __restrict__ B1, short* __restrict__ B2, short* __restrict__ B3,
    short* __restrict__ Wfc, short* __restrict__ Wg1, short* __restrict__ Wg2) {
  int idx = blockIdx.x * 256 + threadIdx.x;
  if (idx < 2048) {  // B1f: frag f = nt*2+ks', elem = lane*8+j
    int j = idx & 7, lane = (idx >> 3) & 63, f = idx >> 9;
    int nt = f >> 1, ksp = f & 1;
    int col = lane & 15, quad = lane >> 4;
    int k = ksp * 32 + quad * 8 + j;
    int t = k >> 2, ic = k & 3;
    int oc = nt * 16 + col;
    float v = (t < 9 && ic < 3) ? w_c1[(oc * 3 + ic) * 9 + t] : 0.0f;
    B1[idx] = f2bf(v);
  } else if (idx < 20480) {  // B2f: frag f = nt*9+t
    int i2 = idx - 2048;
    int j = i2 & 7, lane = (i2 >> 3) & 63, f = i2 >> 9;
    int nt = f / 9, t = f - nt * 9;
    int col = lane & 15, quad = lane >> 4;
    int oc = nt * 16 + col, ic = quad * 8 + j;
    B2[i2] = f2bf(w_c2[(oc * 32 + ic) * 9 + t]);
  } else if (idx < 94208) {  // B3f: frag f = ng*18+ks
    int i3 = idx - 20480;
    int j = i3 & 7, lane = (i3 >> 3) & 63, f = i3 >> 9;
    int ng = f / 18, ks = f - ng * 18;
    int col = lane & 15, quad = lane >> 4;
    int oc = ng * 16 + col;
    int k = ks * 32 + quad * 8 + j;
    int t = k >> 6, ic = k & 63;
    B3[i3] = f2bf(w_c3[(oc * 64 + ic) * 9 + t]);
  } else if (idx < 110592) {
    int i = idx - 94208; Wfc[i] = f2bf(w_fc[i]);
  } else if (idx < 126976) {
    int i = idx - 110592; Wg1[i] = f2bf(w_g1[i]);
  } else if (idx < 143360) {
    int i = idx - 126976; Wg2[i] = f2bf(w_g2[i]);
  }
}

// ---------- conv stack: 1024 blocks x 256 thr, 16 samples/block ----------
// (byte-identical to r19: pair-split P2, ng-split P3, c2all stride 264)
__global__ __launch_bounds__(256) void conv_all(
    const float* __restrict__ x, const short* __restrict__ B1f,
    const short* __restrict__ B2f, const short* __restrict__ B3f,
    const float* __restrict__ b1, const float* __restrict__ g1c,
    const float* __restrict__ e1, const float* __restrict__ b2,
    const float* __restrict__ g2c, const float* __restrict__ e2,
    const float* __restrict__ b3, const float* __restrict__ g3c,
    const float* __restrict__ e3, short* __restrict__ c3) {
  __shared__ short frames[4 * 800];   // 2 padded frames per wave, 6.4 KB
  __shared__ short c1all[16 * 512];   // conv1 out, 16 samples shared, 16 KB
  __shared__ short c2all[16 * 264];   // conv2 out, PADDED stride 264, 8.25 KB
  const int tid = threadIdx.x;
  const int lane = tid & 63, w = tid >> 6;   // w in [0,4)
  const int col = lane & 15, quad = lane >> 4;
  const int m = lane & 15;
  const int s0 = blockIdx.x * 16;            // block's first sample

  short* frameW = frames + w * 800;
  const uint2 z2 = {0u, 0u};
  const bf16x8 zf = {0, 0, 0, 0, 0, 0, 0, 0};

  // ================= P0+P1: conv1, wave w -> samples 4w..4w+3 ==============
  {
    bf16x8 Bf1[2][2];
#pragma unroll
    for (int nt = 0; nt < 2; ++nt)
#pragma unroll
      for (int ks = 0; ks < 2; ++ks)
        Bf1[nt][ks] = *(const bf16x8*)(B1f + ((nt * 2 + ks) << 9) + lane * 8);
    float Abn1[2], Cbn1[2];
#pragma unroll
    for (int nt = 0; nt < 2; ++nt) {
      int oc = nt * 16 + col;
      float a = g1c[oc] * rsqrtf(1.0f + 1e-5f);
      Abn1[nt] = a;
      Cbn1[nt] = fmaf(b1[oc], a, e1[oc]);
    }
    const int t0 = 2 * quad, t1 = t0 + 1;
    const int ky0 = t0 / 3, kx0 = t0 - 3 * (t0 / 3);
    const int ky1 = t1 / 3, kx1 = t1 - 3 * (t1 / 3);
    const int pl = m >> 2, sub1 = m & 3;
    const int dy = sub1 >> 1, dx = sub1 & 1;
    const int fy = lane >> 3, fx = lane & 7;

    // zero this wave's frame slots once (halo stays 0)
    for (int i = lane; i < 100; i += 64)
      *(uint4*)(frameW + i * 8) = (uint4){0, 0, 0, 0};

    for (int c = 0; c < 2; ++c) {
#pragma unroll
      for (int sl = 0; sl < 2; ++sl) {
        const float* xb = x + (s0 + 4 * w + 2 * c + sl) * 192 + lane;
        ushort4 o;
        o.x = (unsigned short)f2bf(xb[0]);
        o.y = (unsigned short)f2bf(xb[64]);
        o.z = (unsigned short)f2bf(xb[128]);
        o.w = 0;
        *(ushort4*)(frameW + sl * 400 + ((fy + 1) * 10 + fx + 1) * 4) = o;
      }
#pragma unroll
      for (int sl = 0; sl < 2; ++sl) {
        const short* xb = frameW + sl * 400;
        short* c1row = c1all + (4 * w + 2 * c + sl) * 512;
#pragma unroll
        for (int tile = 0; tile < 4; ++tile) {
          const int pi = tile * 4 + pl;
          const int py = pi >> 2, px = pi & 3;
          const int cy = 2 * py + dy, cx = 2 * px + dx;
          union { bf16x8 v; uint2 u[2]; } a0, a1;
          a0.u[0] = *(const uint2*)(xb + ((cy + ky0) * 10 + cx + kx0) * 4);
          a0.u[1] = *(const uint2*)(xb + ((cy + ky1) * 10 + cx + kx1) * 4);
          uint2 u8 = *(const uint2*)(xb + ((cy + 2) * 10 + cx + 2) * 4);
          a1.u[0] = (quad == 0) ? u8 : z2;
          a1.u[1] = z2;
          f32x4 acc0 = {0, 0, 0, 0}, acc1 = {0, 0, 0, 0};
          acc0 = __builtin_amdgcn_mfma_f32_16x16x32_bf16(a0.v, Bf1[0][0], acc0, 0, 0, 0);
          acc0 = __builtin_amdgcn_mfma_f32_16x16x32_bf16(a1.v, Bf1[0][1], acc0, 0, 0, 0);
          acc1 = __builtin_amdgcn_mfma_f32_16x16x32_bf16(a0.v, Bf1[1][0], acc1, 0, 0, 0);
          acc1 = __builtin_amdgcn_mfma_f32_16x16x32_bf16(a1.v, Bf1[1][1], acc1, 0, 0, 0);
          const int piq = tile * 4 + quad;
#pragma unroll
          for (int nt = 0; nt < 2; ++nt) {
            f32x4 acc = nt ? acc1 : acc0;
            float p0 = fmaf(acc[0], Abn1[nt], Cbn1[nt]);
            float p1 = fmaf(acc[1], Abn1[nt], Cbn1[nt]);
            float p2 = fmaf(acc[2], Abn1[nt], Cbn1[nt]);
            float p3 = fmaf(acc[3], Abn1[nt], Cbn1[nt]);
            float mx = fmaxf(fmaxf(fmaxf(p0, p1), fmaxf(p2, p3)), 0.0f);
            c1row[piq * 32 + nt * 16 + col] = f2bf(mx);
          }
        }
      }
    }
  }
  __syncthreads();

  // ============ P2: conv2 pair-split — Bf2[2][9]=72 regs RESIDENT ==========
  {
    const int p = w & 1;          // nt pair: {2p, 2p+1}
    const int h = w >> 1;         // sample half: 8h..8h+7
    bf16x8 Bf2[2][9];
#pragma unroll
    for (int j = 0; j < 2; ++j)
#pragma unroll
      for (int t = 0; t < 9; ++t)
        Bf2[j][t] = *(const bf16x8*)(B2f + (((2 * p + j) * 9 + t) << 9) + lane * 8);
    float Abn2[2], Cbn2[2];
#pragma unroll
    for (int j = 0; j < 2; ++j) {
      int oc = (2 * p + j) * 16 + col;
      float a = g2c[oc] * rsqrtf(1.0f + 1e-5f);
      Abn2[j] = a;
      Cbn2[j] = fmaf(b2[oc], a, e2[oc]);
    }
    int off2[9];
    bool valid2[9];
    {
      const int q2 = m >> 2, sub = m & 3;
      const int cy2 = 2 * (q2 >> 1) + (sub >> 1);
      const int cx2 = 2 * (q2 & 1) + (sub & 1);
#pragma unroll
      for (int t = 0; t < 9; ++t) {
        int ky = t / 3, kx = t - 3 * (t / 3);
        int yy = cy2 + ky - 1, xx = cx2 + kx - 1;
        valid2[t] = ((unsigned)yy < 4u) && ((unsigned)xx < 4u);
        int yc = min(max(yy, 0), 3), xc = min(max(xx, 0), 3);
        off2[t] = (yc * 4 + xc) * 32 + quad * 8;
      }
    }
    for (int s = 0; s < 8; ++s) {
      const int si = 8 * h + s;
      const short* ib = c1all + si * 512;
      f32x4 acc0 = {0, 0, 0, 0}, acc1 = {0, 0, 0, 0};
#pragma unroll
      for (int t = 0; t < 9; ++t) {
        bf16x8 a = *(const bf16x8*)(ib + off2[t]);
        if (!valid2[t]) a = zf;
        acc0 = __builtin_amdgcn_mfma_f32_16x16x32_bf16(a, Bf2[0][t], acc0, 0, 0, 0);
        acc1 = __builtin_amdgcn_mfma_f32_16x16x32_bf16(a, Bf2[1][t], acc1, 0, 0, 0);
      }
#pragma unroll
      for (int j = 0; j < 2; ++j) {
        f32x4 acc = j ? acc1 : acc0;
        float p0 = fmaf(acc[0], Abn2[j], Cbn2[j]);
        float p1 = fmaf(acc[1], Abn2[j], Cbn2[j]);
        float p2 = fmaf(acc[2], Abn2[j], Cbn2[j]);
        float p3 = fmaf(acc[3], Abn2[j], Cbn2[j]);
        float mx = fmaxf(fmaxf(fmaxf(p0, p1), fmaxf(p2, p3)), 0.0f);
        c2all[si * 264 + quad * 64 + (2 * p + j) * 16 + col] = f2bf(mx);
      }
    }
  }
  __syncthreads();

  // ====== P3: conv3 ng-split — Bng[18]=72 regs loaded ONCE per ng ==========
  {
    const int cp = m & 3, sl3 = m >> 2;
    const int cy = cp >> 1, cx = cp & 1;
    int off3[18];
    bool val3[18];
#pragma unroll
    for (int ks = 0; ks < 18; ++ks) {
      int t = ks >> 1;
      int ky = t / 3, kx = t - 3 * (t / 3);
      int iy = cy + ky - 1, ix = cx + kx - 1;
      val3[ks] = ((unsigned)iy < 2u) && ((unsigned)ix < 2u);
      int iyc = min(max(iy, 0), 1), ixc = min(max(ix, 0), 1);
      off3[ks] = (iyc * 2 + ixc) * 64 + (ks & 1) * 32 + quad * 8;
    }
    for (int pass = 0; pass < 2; ++pass) {
      const int ng = w + 4 * pass;
      bf16x8 Bng[18];
#pragma unroll
      for (int ks = 0; ks < 18; ++ks)
        Bng[ks] = *(const bf16x8*)(B3f + (((ng * 18 + ks) << 6) + lane) * 8);
      const int oc = ng * 16 + col;
      const float a3 = g3c[oc] * rsqrtf(1.0f + 1e-5f);
      const float c3c = fmaf(b3[oc], a3, e3[oc]);
#pragma unroll
      for (int g2 = 0; g2 < 2; ++g2) {
        const int g0 = 2 * g2, g1 = g0 + 1;
        const short* base0 = c2all + (4 * g0 + sl3) * 264;
        const short* base1 = c2all + (4 * g1 + sl3) * 264;
        f32x4 ac0 = {0, 0, 0, 0}, ac1 = {0, 0, 0, 0};
#pragma unroll
        for (int ks = 0; ks < 18; ++ks) {
          bf16x8 a0 = *(const bf16x8*)(base0 + off3[ks]);
          bf16x8 a1 = *(const bf16x8*)(base1 + off3[ks]);
          if (!val3[ks]) { a0 = zf; a1 = zf; }
          ac0 = __builtin_amdgcn_mfma_f32_16x16x32_bf16(a0, Bng[ks], ac0, 0, 0, 0);
          ac1 = __builtin_amdgcn_mfma_f32_16x16x32_bf16(a1, Bng[ks], ac1, 0, 0, 0);
        }
#pragma unroll
        for (int ch = 0; ch < 2; ++ch) {
          const int g = ch ? g1 : g0;
          f32x4 acc = ch ? ac1 : ac0;
          const int sample = s0 + 4 * g + quad;
          float p0 = fmaf(acc[0], a3, c3c);
          float p1 = fmaf(acc[1], a3, c3c);
          float p2 = fmaf(acc[2], a3, c3c);
          float p3 = fmaf(acc[3], a3, c3c);
          float mx = fmaxf(fmaxf(fmaxf(p0, p1), fmaxf(p2, p3)), 0.0f);
          c3[sample * 128 + oc] = f2bf(mx);
        }
      }
    }
  }
}

// ---------- fused dense tail: TWO blocks (512 thr) per batch ----------
// Both blocks of a pair compute the identical deterministic pipeline for
// batch b = blockIdx>>1; each writes only output rows [32*half, 32*half+32).
__global__ __launch_bounds__(512) void fused_dense(
    const short* __restrict__ c3, const float* __restrict__ gso,
    const short* __restrict__ Wfc, const short* __restrict__ Wg1,
    const short* __restrict__ Wg2, const float* __restrict__ b_fc,
    const float* __restrict__ b_g1, const float* __restrict__ b_g2,
    const float* __restrict__ w_o, const float* __restrict__ b_o,
    float* __restrict__ out) {
  __shared__ short sAct[64 * 136];
  __shared__ short sT[128 * 72];
  __shared__ short sAhat[64 * 72];
  __shared__ float sDinv[64];
  __shared__ float sWo[640];
  const int tid = threadIdx.x;
  const int b = blockIdx.x >> 1;
  const int half = blockIdx.x & 1;
  float* sG = (float*)sT;
  for (int i = tid; i < 4096; i += 512) sG[i] = gso[b * 4096 + i];
  for (int i = tid; i < 640; i += 512) sWo[i] = w_o[i];
  __syncthreads();
  if (tid < 64) {
    float ssum = 1.0f;
    for (int j = 0; j < 64; ++j) ssum += sG[j * 64 + tid];
    sDinv[tid] = rsqrtf(ssum);
  }
  __syncthreads();
  for (int i = tid; i < 4096; i += 512) {
    int r = i >> 6, c = i & 63;
    float v = sDinv[r] * (sG[i] + (r == c ? 1.0f : 0.0f)) * sDinv[c];
    sAhat[r * 72 + c] = f2bf(v);
  }
  for (int i = tid; i < 1024; i += 512) {
    int r = i >> 4, seg = i & 15;
    *(bf16x8*)(sAct + r * 136 + seg * 8) =
        *(const bf16x8*)(c3 + (b * 64 + r) * 128 + seg * 8);
  }
  __syncthreads();
  const int lane = tid & 63, w8 = tid >> 6;
  const int rg = w8 >> 1, nh = w8 & 1;
  const int col = lane & 15, quad = lane >> 4;
  const int arow = (rg * 16 + col) * 136;
  const int crow0 = (rg * 16 + quad * 4) * 136;
  bf16x8 A[4];
  f32x4 acc[4];

  // ---- FC ----
#pragma unroll
  for (int ks = 0; ks < 4; ++ks)
    A[ks] = *(const bf16x8*)(sAct + arow + ks * 32 + quad * 8);
  __syncthreads();
#pragma unroll
  for (int i = 0; i < 4; ++i) acc[i] = (f32x4){0, 0, 0, 0};
#pragma unroll
  for (int ntl = 0; ntl < 4; ++ntl) {
    const int n = (nh * 4 + ntl) * 16 + col;
#pragma unroll
    for (int ks = 0; ks < 4; ++ks) {
      bf16x8 bb = *(const bf16x8*)(Wfc + n * 128 + ks * 32 + quad * 8);
      acc[ntl] = __builtin_amdgcn_mfma_f32_16x16x32_bf16(A[ks], bb, acc[ntl], 0, 0, 0);
    }
  }
#pragma unroll
  for (int ntl = 0; ntl < 4; ++ntl) {
    const int n = (nh * 4 + ntl) * 16 + col;
    const float bv = b_fc[n];
#pragma unroll
    for (int reg = 0; reg < 4; ++reg)
      sAct[crow0 + reg * 136 + n] = f2bf(fmaxf(acc[ntl][reg] + bv, 0.0f));
  }
  __syncthreads();

  // ---- G1 -> sT (transposed) ----
#pragma unroll
  for (int ks = 0; ks < 4; ++ks)
    A[ks] = *(const bf16x8*)(sAct + arow + ks * 32 + quad * 8);
#pragma unroll
  for (int i = 0; i < 4; ++i) acc[i] = (f32x4){0, 0, 0, 0};
#pragma unroll
  for (int ntl = 0; ntl < 4; ++ntl) {
    const int n = (nh * 4 + ntl) * 16 + col;
#pragma unroll
    for (int ks = 0; ks < 4; ++ks) {
      bf16x8 bb = *(const bf16x8*)(Wg1 + n * 128 + ks * 32 + quad * 8);
      acc[ntl] = __builtin_amdgcn_mfma_f32_16x16x32_bf16(A[ks], bb, acc[ntl], 0, 0, 0);
    }
  }
#pragma unroll
  for (int ntl = 0; ntl < 4; ++ntl) {
    const int n = (nh * 4 + ntl) * 16 + col;
    ushort4 pk;
    pk.x = (unsigned short)f2bf(acc[ntl][0]);
    pk.y = (unsigned short)f2bf(acc[ntl][1]);
    pk.z = (unsigned short)f2bf(acc[ntl][2]);
    pk.w = (unsigned short)f2bf(acc[ntl][3]);
    *(ushort4*)(sT + n * 72 + rg * 16 + quad * 4) = pk;
  }
  __syncthreads();

  // ---- AGG1 ----
  bf16x8 Ah[2];
#pragma unroll
  for (int ks = 0; ks < 2; ++ks)
    Ah[ks] = *(const bf16x8*)(sAhat + (rg * 16 + col) * 72 + ks * 32 + quad * 8);
#pragma unroll
  for (int i = 0; i < 4; ++i) acc[i] = (f32x4){0, 0, 0, 0};
#pragma unroll
  for (int ntl = 0; ntl < 4; ++ntl) {
    const int n = (nh * 4 + ntl) * 16 + col;
#pragma unroll
    for (int ks = 0; ks < 2; ++ks) {
      bf16x8 bb = *(const bf16x8*)(sT + n * 72 + ks * 32 + quad * 8);
      acc[ntl] = __builtin_amdgcn_mfma_f32_16x16x32_bf16(Ah[ks], bb, acc[ntl], 0, 0, 0);
    }
  }
#pragma unroll
  for (int ntl = 0; ntl < 4; ++ntl) {
    const int n = (nh * 4 + ntl) * 16 + col;
    const float bv = b_g1[n];
#pragma unroll
    for (int reg = 0; reg < 4; ++reg)
      sAct[crow0 + reg * 136 + n] = f2bf(fmaxf(acc[ntl][reg] + bv, 0.0f));
  }
  __syncthreads();

  // ---- G2 -> sT ----
#pragma unroll
  for (int ks = 0; ks < 4; ++ks)
    A[ks] = *(const bf16x8*)(sAct + arow + ks * 32 + quad * 8);
#pragma unroll
  for (int i = 0; i < 4; ++i) acc[i] = (f32x4){0, 0, 0, 0};
#pragma unroll
  for (int ntl = 0; ntl < 4; ++ntl) {
    const int n = (nh * 4 + ntl) * 16 + col;
#pragma unroll
    for (int ks = 0; ks < 4; ++ks) {
      bf16x8 bb = *(const bf16x8*)(Wg2 + n * 128 + ks * 32 + quad * 8);
      acc[ntl] = __builtin_amdgcn_mfma_f32_16x16x32_bf16(A[ks], bb, acc[ntl], 0, 0, 0);
    }
  }
#pragma unroll
  for (int ntl = 0; ntl < 4; ++ntl) {
    const int n = (nh * 4 + ntl) * 16 + col;
    ushort4 pk;
    pk.x = (unsigned short)f2bf(acc[ntl][0]);
    pk.y = (unsigned short)f2bf(acc[ntl][1]);
    pk.z = (unsigned short)f2bf(acc[ntl][2]);
    pk.w = (unsigned short)f2bf(acc[ntl][3]);
    *(ushort4*)(sT + n * 72 + rg * 16 + quad * 4) = pk;
  }
  __syncthreads();

  // ---- AGG2 ----
#pragma unroll
  for (int i = 0; i < 4; ++i) acc[i] = (f32x4){0, 0, 0, 0};
#pragma unroll
  for (int ntl = 0; ntl < 4; ++ntl) {
    const int n = (nh * 4 + ntl) * 16 + col;
#pragma unroll
    for (int ks = 0; ks < 2; ++ks) {
      bf16x8 bb = *(const bf16x8*)(sT + n * 72 + ks * 32 + quad * 8);
      acc[ntl] = __builtin_amdgcn_mfma_f32_16x16x32_bf16(Ah[ks], bb, acc[ntl], 0, 0, 0);
    }
  }
#pragma unroll
  for (int ntl = 0; ntl < 4; ++ntl) {
    const int n = (nh * 4 + ntl) * 16 + col;
    const float bv = b_g2[n];
#pragma unroll
    for (int reg = 0; reg < 4; ++reg)
      sAct[crow0 + reg * 136 + n] = f2bf(fmaxf(acc[ntl][reg] + bv, 0.0f));
  }
  __syncthreads();

  // ---- HEAD: this block writes only rows [32*half, 32*half+32) ----
  if (tid < 160) {
    const int j = half * 32 + tid / 5, o = tid - 5 * (tid / 5);
    float a0 = 0.0f;
#pragma unroll
    for (int k8 = 0; k8 < 16; ++k8) {
      union { bf16x8 v; unsigned short u[8]; } h;
      h.v = *(const bf16x8*)(sAct + j * 136 + k8 * 8);
#pragma unroll
      for (int jj = 0; jj < 8; ++jj)
        a0 = fmaf(bf2f(h.u[jj]), sWo[o * 128 + k8 * 8 + jj], a0);
    }
    out[(b * 64 + j) * 5 + o] = a0 + b_o[o];
  }
}

extern "C" void kernel_launch(void* const* d_in, const int* in_sizes, int n_in,
                              void* d_out, int out_size, void* d_ws, size_t ws_size,
                              hipStream_t stream) {
  const float* x    = (const float*)d_in[0];
  const float* gso  = (const float*)d_in[1];
  const float* w_c1 = (const float*)d_in[2];
  const float* b_c1 = (const float*)d_in[3];
  const float* g_b1 = (const float*)d_in[4];
  const float* e_b1 = (const float*)d_in[5];
  const float* w_c2 = (const float*)d_in[6];
  const float* b_c2 = (const float*)d_in[7];
  const float* g_b2 = (const float*)d_in[8];
  const float* e_b2 = (const float*)d_in[9];
  const float* w_c3 = (const float*)d_in[10];
  const float* b_c3 = (const float*)d_in[11];
  const float* g_b3 = (const float*)d_in[12];
  const float* e_b3 = (const float*)d_in[13];
  const float* w_fc = (const float*)d_in[14];
  const float* b_fc = (const float*)d_in[15];
  const float* w_g1 = (const float*)d_in[16];
  const float* b_g1 = (const float*)d_in[17];
  const float* w_g2 = (const float*)d_in[18];
  const float* b_g2 = (const float*)d_in[19];
  const float* w_o  = (const float*)d_in[20];
  const float* b_o  = (const float*)d_in[21];
  float* out = (float*)d_out;
  char* ws = (char*)d_ws;

  // workspace layout (bytes) — NO ALIASING, total ~4.5 MB
  short* c3  = (short*)(ws + 0);         //  4,194,304
  short* B1  = (short*)(ws + 4194304);   //  4,096   (fragment order)
  short* B2  = (short*)(ws + 4198400);   //  36,864  (fragment order)
  short* B3  = (short*)(ws + 4235264);   //  147,456 (fragment order)
  short* Wfc = (short*)(ws + 4382720);   //  32,768
  short* Wg1 = (short*)(ws + 4415488);   //  32,768
  short* Wg2 = (short*)(ws + 4448256);   //  32,768

  pack_all<<<560, 256, 0, stream>>>(w_c1, w_c2, w_c3, w_fc, w_g1, w_g2,
                                    B1, B2, B3, Wfc, Wg1, Wg2);
  conv_all<<<1024, 256, 0, stream>>>(x, B1, B2, B3, b_c1, g_b1, e_b1,
                                     b_c2, g_b2, e_b2, b_c3, g_b3, e_b3, c3);
  fused_dense<<<512, 512, 0, stream>>>(c3, gso, Wfc, Wg1, Wg2, b_fc, b_g1,
                                       b_g2, w_o, b_o, out);
}

// Round 13
// 148.480 us; speedup vs baseline: 1.0847x; 1.0847x over previous
//
#include <hip/hip_runtime.h>
#include <math.h>

// Round 21: REVERT to r19 (session-best 150.1us) byte-for-byte. r20's dense
// duplication regressed (+11us: doubled dense HBM traffic + MFMA outweighed
// barrier-bubble savings). r19 = split kernels; conv pair/ng-split fitting the
// 128-VGPR budget (r17) + c2all stride 264 bank pad. The measured response
// surface around this point is concave: occupancy up (r15), ILP up (r18),
// regs up (r13/14), fusion (r11/12), replication (r20) all regress.

typedef __attribute__((ext_vector_type(8))) short bf16x8;
typedef __attribute__((ext_vector_type(4))) float f32x4;

__device__ __forceinline__ short f2bf(float f) {
  union { float f; unsigned u; } v; v.f = f;
  unsigned r = v.u + 0x7fffu + ((v.u >> 16) & 1u);
  return (short)(r >> 16);
}
__device__ __forceinline__ float bf2f(unsigned short u) {
  union { unsigned u; float f; } v; v.u = ((unsigned)u) << 16;
  return v.f;
}

// ---------- all weight packs (fragment order for convs) ----------
__global__ __launch_bounds__(256) void pack_all(
    const float* __restrict__ w_c1, const float* __restrict__ w_c2,
    const float* __restrict__ w_c3, const float* __restrict__ w_fc,
    const float* __restrict__ w_g1, const float* __restrict__ w_g2,
    short* __restrict__ B1, short* __restrict__ B2, short* __restrict__ B3,
    short* __restrict__ Wfc, short* __restrict__ Wg1, short* __restrict__ Wg2) {
  int idx = blockIdx.x * 256 + threadIdx.x;
  if (idx < 2048) {  // B1f: frag f = nt*2+ks', elem = lane*8+j
    int j = idx & 7, lane = (idx >> 3) & 63, f = idx >> 9;
    int nt = f >> 1, ksp = f & 1;
    int col = lane & 15, quad = lane >> 4;
    int k = ksp * 32 + quad * 8 + j;
    int t = k >> 2, ic = k & 3;
    int oc = nt * 16 + col;
    float v = (t < 9 && ic < 3) ? w_c1[(oc * 3 + ic) * 9 + t] : 0.0f;
    B1[idx] = f2bf(v);
  } else if (idx < 20480) {  // B2f: frag f = nt*9+t
    int i2 = idx - 2048;
    int j = i2 & 7, lane = (i2 >> 3) & 63, f = i2 >> 9;
    int nt = f / 9, t = f - nt * 9;
    int col = lane & 15, quad = lane >> 4;
    int oc = nt * 16 + col, ic = quad * 8 + j;
    B2[i2] = f2bf(w_c2[(oc * 32 + ic) * 9 + t]);
  } else if (idx < 94208) {  // B3f: frag f = ng*18+ks
    int i3 = idx - 20480;
    int j = i3 & 7, lane = (i3 >> 3) & 63, f = i3 >> 9;
    int ng = f / 18, ks = f - ng * 18;
    int col = lane & 15, quad = lane >> 4;
    int oc = ng * 16 + col;
    int k = ks * 32 + quad * 8 + j;
    int t = k >> 6, ic = k & 63;
    B3[i3] = f2bf(w_c3[(oc * 64 + ic) * 9 + t]);
  } else if (idx < 110592) {
    int i = idx - 94208; Wfc[i] = f2bf(w_fc[i]);
  } else if (idx < 126976) {
    int i = idx - 110592; Wg1[i] = f2bf(w_g1[i]);
  } else if (idx < 143360) {
    int i = idx - 126976; Wg2[i] = f2bf(w_g2[i]);
  }
}

// ---------- conv stack: 1024 blocks x 256 thr, 16 samples/block ----------
__global__ __launch_bounds__(256) void conv_all(
    const float* __restrict__ x, const short* __restrict__ B1f,
    const short* __restrict__ B2f, const short* __restrict__ B3f,
    const float* __restrict__ b1, const float* __restrict__ g1c,
    const float* __restrict__ e1, const float* __restrict__ b2,
    const float* __restrict__ g2c, const float* __restrict__ e2,
    const float* __restrict__ b3, const float* __restrict__ g3c,
    const float* __restrict__ e3, short* __restrict__ c3) {
  __shared__ short frames[4 * 800];   // 2 padded frames per wave, 6.4 KB
  __shared__ short c1all[16 * 512];   // conv1 out, 16 samples shared, 16 KB
  __shared__ short c2all[16 * 264];   // conv2 out, PADDED stride 264, 8.25 KB
  const int tid = threadIdx.x;
  const int lane = tid & 63, w = tid >> 6;   // w in [0,4)
  const int col = lane & 15, quad = lane >> 4;
  const int m = lane & 15;
  const int s0 = blockIdx.x * 16;            // block's first sample

  short* frameW = frames + w * 800;
  const uint2 z2 = {0u, 0u};
  const bf16x8 zf = {0, 0, 0, 0, 0, 0, 0, 0};

  // ================= P0+P1: conv1, wave w -> samples 4w..4w+3 ==============
  {
    bf16x8 Bf1[2][2];
#pragma unroll
    for (int nt = 0; nt < 2; ++nt)
#pragma unroll
      for (int ks = 0; ks < 2; ++ks)
        Bf1[nt][ks] = *(const bf16x8*)(B1f + ((nt * 2 + ks) << 9) + lane * 8);
    float Abn1[2], Cbn1[2];
#pragma unroll
    for (int nt = 0; nt < 2; ++nt) {
      int oc = nt * 16 + col;
      float a = g1c[oc] * rsqrtf(1.0f + 1e-5f);
      Abn1[nt] = a;
      Cbn1[nt] = fmaf(b1[oc], a, e1[oc]);
    }
    const int t0 = 2 * quad, t1 = t0 + 1;
    const int ky0 = t0 / 3, kx0 = t0 - 3 * (t0 / 3);
    const int ky1 = t1 / 3, kx1 = t1 - 3 * (t1 / 3);
    const int pl = m >> 2, sub1 = m & 3;
    const int dy = sub1 >> 1, dx = sub1 & 1;
    const int fy = lane >> 3, fx = lane & 7;

    // zero this wave's frame slots once (halo stays 0)
    for (int i = lane; i < 100; i += 64)
      *(uint4*)(frameW + i * 8) = (uint4){0, 0, 0, 0};

    for (int c = 0; c < 2; ++c) {
#pragma unroll
      for (int sl = 0; sl < 2; ++sl) {
        const float* xb = x + (s0 + 4 * w + 2 * c + sl) * 192 + lane;
        ushort4 o;
        o.x = (unsigned short)f2bf(xb[0]);
        o.y = (unsigned short)f2bf(xb[64]);
        o.z = (unsigned short)f2bf(xb[128]);
        o.w = 0;
        *(ushort4*)(frameW + sl * 400 + ((fy + 1) * 10 + fx + 1) * 4) = o;
      }
#pragma unroll
      for (int sl = 0; sl < 2; ++sl) {
        const short* xb = frameW + sl * 400;
        short* c1row = c1all + (4 * w + 2 * c + sl) * 512;
#pragma unroll
        for (int tile = 0; tile < 4; ++tile) {
          const int pi = tile * 4 + pl;
          const int py = pi >> 2, px = pi & 3;
          const int cy = 2 * py + dy, cx = 2 * px + dx;
          union { bf16x8 v; uint2 u[2]; } a0, a1;
          a0.u[0] = *(const uint2*)(xb + ((cy + ky0) * 10 + cx + kx0) * 4);
          a0.u[1] = *(const uint2*)(xb + ((cy + ky1) * 10 + cx + kx1) * 4);
          uint2 u8 = *(const uint2*)(xb + ((cy + 2) * 10 + cx + 2) * 4);
          a1.u[0] = (quad == 0) ? u8 : z2;
          a1.u[1] = z2;
          f32x4 acc0 = {0, 0, 0, 0}, acc1 = {0, 0, 0, 0};
          acc0 = __builtin_amdgcn_mfma_f32_16x16x32_bf16(a0.v, Bf1[0][0], acc0, 0, 0, 0);
          acc0 = __builtin_amdgcn_mfma_f32_16x16x32_bf16(a1.v, Bf1[0][1], acc0, 0, 0, 0);
          acc1 = __builtin_amdgcn_mfma_f32_16x16x32_bf16(a0.v, Bf1[1][0], acc1, 0, 0, 0);
          acc1 = __builtin_amdgcn_mfma_f32_16x16x32_bf16(a1.v, Bf1[1][1], acc1, 0, 0, 0);
          const int piq = tile * 4 + quad;
#pragma unroll
          for (int nt = 0; nt < 2; ++nt) {
            f32x4 acc = nt ? acc1 : acc0;
            float p0 = fmaf(acc[0], Abn1[nt], Cbn1[nt]);
            float p1 = fmaf(acc[1], Abn1[nt], Cbn1[nt]);
            float p2 = fmaf(acc[2], Abn1[nt], Cbn1[nt]);
            float p3 = fmaf(acc[3], Abn1[nt], Cbn1[nt]);
            float mx = fmaxf(fmaxf(fmaxf(p0, p1), fmaxf(p2, p3)), 0.0f);
            c1row[piq * 32 + nt * 16 + col] = f2bf(mx);
          }
        }
      }
    }
  }
  __syncthreads();

  // ============ P2: conv2 pair-split — Bf2[2][9]=72 regs RESIDENT ==========
  {
    const int p = w & 1;          // nt pair: {2p, 2p+1}
    const int h = w >> 1;         // sample half: 8h..8h+7
    bf16x8 Bf2[2][9];
#pragma unroll
    for (int j = 0; j < 2; ++j)
#pragma unroll
      for (int t = 0; t < 9; ++t)
        Bf2[j][t] = *(const bf16x8*)(B2f + (((2 * p + j) * 9 + t) << 9) + lane * 8);
    float Abn2[2], Cbn2[2];
#pragma unroll
    for (int j = 0; j < 2; ++j) {
      int oc = (2 * p + j) * 16 + col;
      float a = g2c[oc] * rsqrtf(1.0f + 1e-5f);
      Abn2[j] = a;
      Cbn2[j] = fmaf(b2[oc], a, e2[oc]);
    }
    int off2[9];
    bool valid2[9];
    {
      const int q2 = m >> 2, sub = m & 3;
      const int cy2 = 2 * (q2 >> 1) + (sub >> 1);
      const int cx2 = 2 * (q2 & 1) + (sub & 1);
#pragma unroll
      for (int t = 0; t < 9; ++t) {
        int ky = t / 3, kx = t - 3 * (t / 3);
        int yy = cy2 + ky - 1, xx = cx2 + kx - 1;
        valid2[t] = ((unsigned)yy < 4u) && ((unsigned)xx < 4u);
        int yc = min(max(yy, 0), 3), xc = min(max(xx, 0), 3);
        off2[t] = (yc * 4 + xc) * 32 + quad * 8;
      }
    }
    for (int s = 0; s < 8; ++s) {
      const int si = 8 * h + s;
      const short* ib = c1all + si * 512;
      f32x4 acc0 = {0, 0, 0, 0}, acc1 = {0, 0, 0, 0};
#pragma unroll
      for (int t = 0; t < 9; ++t) {
        bf16x8 a = *(const bf16x8*)(ib + off2[t]);
        if (!valid2[t]) a = zf;
        acc0 = __builtin_amdgcn_mfma_f32_16x16x32_bf16(a, Bf2[0][t], acc0, 0, 0, 0);
        acc1 = __builtin_amdgcn_mfma_f32_16x16x32_bf16(a, Bf2[1][t], acc1, 0, 0, 0);
      }
#pragma unroll
      for (int j = 0; j < 2; ++j) {
        f32x4 acc = j ? acc1 : acc0;
        float p0 = fmaf(acc[0], Abn2[j], Cbn2[j]);
        float p1 = fmaf(acc[1], Abn2[j], Cbn2[j]);
        float p2 = fmaf(acc[2], Abn2[j], Cbn2[j]);
        float p3 = fmaf(acc[3], Abn2[j], Cbn2[j]);
        float mx = fmaxf(fmaxf(fmaxf(p0, p1), fmaxf(p2, p3)), 0.0f);
        c2all[si * 264 + quad * 64 + (2 * p + j) * 16 + col] = f2bf(mx);
      }
    }
  }
  __syncthreads();

  // ====== P3: conv3 ng-split — Bng[18]=72 regs loaded ONCE per ng ==========
  {
    const int cp = m & 3, sl3 = m >> 2;
    const int cy = cp >> 1, cx = cp & 1;
    int off3[18];
    bool val3[18];
#pragma unroll
    for (int ks = 0; ks < 18; ++ks) {
      int t = ks >> 1;
      int ky = t / 3, kx = t - 3 * (t / 3);
      int iy = cy + ky - 1, ix = cx + kx - 1;
      val3[ks] = ((unsigned)iy < 2u) && ((unsigned)ix < 2u);
      int iyc = min(max(iy, 0), 1), ixc = min(max(ix, 0), 1);
      off3[ks] = (iyc * 2 + ixc) * 64 + (ks & 1) * 32 + quad * 8;
    }
    for (int pass = 0; pass < 2; ++pass) {
      const int ng = w + 4 * pass;
      bf16x8 Bng[18];
#pragma unroll
      for (int ks = 0; ks < 18; ++ks)
        Bng[ks] = *(const bf16x8*)(B3f + (((ng * 18 + ks) << 6) + lane) * 8);
      const int oc = ng * 16 + col;
      const float a3 = g3c[oc] * rsqrtf(1.0f + 1e-5f);
      const float c3c = fmaf(b3[oc], a3, e3[oc]);
#pragma unroll
      for (int g2 = 0; g2 < 2; ++g2) {
        const int g0 = 2 * g2, g1 = g0 + 1;
        const short* base0 = c2all + (4 * g0 + sl3) * 264;
        const short* base1 = c2all + (4 * g1 + sl3) * 264;
        f32x4 ac0 = {0, 0, 0, 0}, ac1 = {0, 0, 0, 0};
#pragma unroll
        for (int ks = 0; ks < 18; ++ks) {
          bf16x8 a0 = *(const bf16x8*)(base0 + off3[ks]);
          bf16x8 a1 = *(const bf16x8*)(base1 + off3[ks]);
          if (!val3[ks]) { a0 = zf; a1 = zf; }
          ac0 = __builtin_amdgcn_mfma_f32_16x16x32_bf16(a0, Bng[ks], ac0, 0, 0, 0);
          ac1 = __builtin_amdgcn_mfma_f32_16x16x32_bf16(a1, Bng[ks], ac1, 0, 0, 0);
        }
#pragma unroll
        for (int ch = 0; ch < 2; ++ch) {
          const int g = ch ? g1 : g0;
          f32x4 acc = ch ? ac1 : ac0;
          const int sample = s0 + 4 * g + quad;
          float p0 = fmaf(acc[0], a3, c3c);
          float p1 = fmaf(acc[1], a3, c3c);
          float p2 = fmaf(acc[2], a3, c3c);
          float p3 = fmaf(acc[3], a3, c3c);
          float mx = fmaxf(fmaxf(fmaxf(p0, p1), fmaxf(p2, p3)), 0.0f);
          c3[sample * 128 + oc] = f2bf(mx);
        }
      }
    }
  }
}

// ---------- fused dense tail: one block (512 thr, 8 waves) per batch ----------
// (round-10 verified kernel, byte-identical)
__global__ __launch_bounds__(512) void fused_dense(
    const short* __restrict__ c3, const float* __restrict__ gso,
    const short* __restrict__ Wfc, const short* __restrict__ Wg1,
    const short* __restrict__ Wg2, const float* __restrict__ b_fc,
    const float* __restrict__ b_g1, const float* __restrict__ b_g2,
    const float* __restrict__ w_o, const float* __restrict__ b_o,
    float* __restrict__ out) {
  __shared__ short sAct[64 * 136];
  __shared__ short sT[128 * 72];
  __shared__ short sAhat[64 * 72];
  __shared__ float sDinv[64];
  __shared__ float sWo[640];
  const int tid = threadIdx.x;
  const int b = blockIdx.x;
  float* sG = (float*)sT;
  for (int i = tid; i < 4096; i += 512) sG[i] = gso[b * 4096 + i];
  for (int i = tid; i < 640; i += 512) sWo[i] = w_o[i];
  __syncthreads();
  if (tid < 64) {
    float ssum = 1.0f;
    for (int j = 0; j < 64; ++j) ssum += sG[j * 64 + tid];
    sDinv[tid] = rsqrtf(ssum);
  }
  __syncthreads();
  for (int i = tid; i < 4096; i += 512) {
    int r = i >> 6, c = i & 63;
    float v = sDinv[r] * (sG[i] + (r == c ? 1.0f : 0.0f)) * sDinv[c];
    sAhat[r * 72 + c] = f2bf(v);
  }
  for (int i = tid; i < 1024; i += 512) {
    int r = i >> 4, seg = i & 15;
    *(bf16x8*)(sAct + r * 136 + seg * 8) =
        *(const bf16x8*)(c3 + (b * 64 + r) * 128 + seg * 8);
  }
  __syncthreads();
  const int lane = tid & 63, w8 = tid >> 6;
  const int rg = w8 >> 1, nh = w8 & 1;
  const int col = lane & 15, quad = lane >> 4;
  const int arow = (rg * 16 + col) * 136;
  const int crow0 = (rg * 16 + quad * 4) * 136;
  bf16x8 A[4];
  f32x4 acc[4];

  // ---- FC ----
#pragma unroll
  for (int ks = 0; ks < 4; ++ks)
    A[ks] = *(const bf16x8*)(sAct + arow + ks * 32 + quad * 8);
  __syncthreads();
#pragma unroll
  for (int i = 0; i < 4; ++i) acc[i] = (f32x4){0, 0, 0, 0};
#pragma unroll
  for (int ntl = 0; ntl < 4; ++ntl) {
    const int n = (nh * 4 + ntl) * 16 + col;
#pragma unroll
    for (int ks = 0; ks < 4; ++ks) {
      bf16x8 bb = *(const bf16x8*)(Wfc + n * 128 + ks * 32 + quad * 8);
      acc[ntl] = __builtin_amdgcn_mfma_f32_16x16x32_bf16(A[ks], bb, acc[ntl], 0, 0, 0);
    }
  }
#pragma unroll
  for (int ntl = 0; ntl < 4; ++ntl) {
    const int n = (nh * 4 + ntl) * 16 + col;
    const float bv = b_fc[n];
#pragma unroll
    for (int reg = 0; reg < 4; ++reg)
      sAct[crow0 + reg * 136 + n] = f2bf(fmaxf(acc[ntl][reg] + bv, 0.0f));
  }
  __syncthreads();

  // ---- G1 -> sT (transposed) ----
#pragma unroll
  for (int ks = 0; ks < 4; ++ks)
    A[ks] = *(const bf16x8*)(sAct + arow + ks * 32 + quad * 8);
#pragma unroll
  for (int i = 0; i < 4; ++i) acc[i] = (f32x4){0, 0, 0, 0};
#pragma unroll
  for (int ntl = 0; ntl < 4; ++ntl) {
    const int n = (nh * 4 + ntl) * 16 + col;
#pragma unroll
    for (int ks = 0; ks < 4; ++ks) {
      bf16x8 bb = *(const bf16x8*)(Wg1 + n * 128 + ks * 32 + quad * 8);
      acc[ntl] = __builtin_amdgcn_mfma_f32_16x16x32_bf16(A[ks], bb, acc[ntl], 0, 0, 0);
    }
  }
#pragma unroll
  for (int ntl = 0; ntl < 4; ++ntl) {
    const int n = (nh * 4 + ntl) * 16 + col;
    ushort4 pk;
    pk.x = (unsigned short)f2bf(acc[ntl][0]);
    pk.y = (unsigned short)f2bf(acc[ntl][1]);
    pk.z = (unsigned short)f2bf(acc[ntl][2]);
    pk.w = (unsigned short)f2bf(acc[ntl][3]);
    *(ushort4*)(sT + n * 72 + rg * 16 + quad * 4) = pk;
  }
  __syncthreads();

  // ---- AGG1 ----
  bf16x8 Ah[2];
#pragma unroll
  for (int ks = 0; ks < 2; ++ks)
    Ah[ks] = *(const bf16x8*)(sAhat + (rg * 16 + col) * 72 + ks * 32 + quad * 8);
#pragma unroll
  for (int i = 0; i < 4; ++i) acc[i] = (f32x4){0, 0, 0, 0};
#pragma unroll
  for (int ntl = 0; ntl < 4; ++ntl) {
    const int n = (nh * 4 + ntl) * 16 + col;
#pragma unroll
    for (int ks = 0; ks < 2; ++ks) {
      bf16x8 bb = *(const bf16x8*)(sT + n * 72 + ks * 32 + quad * 8);
      acc[ntl] = __builtin_amdgcn_mfma_f32_16x16x32_bf16(Ah[ks], bb, acc[ntl], 0, 0, 0);
    }
  }
#pragma unroll
  for (int ntl = 0; ntl < 4; ++ntl) {
    const int n = (nh * 4 + ntl) * 16 + col;
    const float bv = b_g1[n];
#pragma unroll
    for (int reg = 0; reg < 4; ++reg)
      sAct[crow0 + reg * 136 + n] = f2bf(fmaxf(acc[ntl][reg] + bv, 0.0f));
  }
  __syncthreads();

  // ---- G2 -> sT ----
#pragma unroll
  for (int ks = 0; ks < 4; ++ks)
    A[ks] = *(const bf16x8*)(sAct + arow + ks * 32 + quad * 8);
#pragma unroll
  for (int i = 0; i < 4; ++i) acc[i] = (f32x4){0, 0, 0, 0};
#pragma unroll
  for (int ntl = 0; ntl < 4; ++ntl) {
    const int n = (nh * 4 + ntl) * 16 + col;
#pragma unroll
    for (int ks = 0; ks < 4; ++ks) {
      bf16x8 bb = *(const bf16x8*)(Wg2 + n * 128 + ks * 32 + quad * 8);
      acc[ntl] = __builtin_amdgcn_mfma_f32_16x16x32_bf16(A[ks], bb, acc[ntl], 0, 0, 0);
    }
  }
#pragma unroll
  for (int ntl = 0; ntl < 4; ++ntl) {
    const int n = (nh * 4 + ntl) * 16 + col;
    ushort4 pk;
    pk.x = (unsigned short)f2bf(acc[ntl][0]);
    pk.y = (unsigned short)f2bf(acc[ntl][1]);
    pk.z = (unsigned short)f2bf(acc[ntl][2]);
    pk.w = (unsigned short)f2bf(acc[ntl][3]);
    *(ushort4*)(sT + n * 72 + rg * 16 + quad * 4) = pk;
  }
  __syncthreads();

  // ---- AGG2 ----
#pragma unroll
  for (int i = 0; i < 4; ++i) acc[i] = (f32x4){0, 0, 0, 0};
#pragma unroll
  for (int ntl = 0; ntl < 4; ++ntl) {
    const int n = (nh * 4 + ntl) * 16 + col;
#pragma unroll
    for (int ks = 0; ks < 2; ++ks) {
      bf16x8 bb = *(const bf16x8*)(sT + n * 72 + ks * 32 + quad * 8);
      acc[ntl] = __builtin_amdgcn_mfma_f32_16x16x32_bf16(Ah[ks], bb, acc[ntl], 0, 0, 0);
    }
  }
#pragma unroll
  for (int ntl = 0; ntl < 4; ++ntl) {
    const int n = (nh * 4 + ntl) * 16 + col;
    const float bv = b_g2[n];
#pragma unroll
    for (int reg = 0; reg < 4; ++reg)
      sAct[crow0 + reg * 136 + n] = f2bf(fmaxf(acc[ntl][reg] + bv, 0.0f));
  }
  __syncthreads();

  // ---- HEAD ----
  if (tid < 320) {
    const int j = tid / 5, o = tid - 5 * j;
    float a0 = 0.0f;
#pragma unroll
    for (int k8 = 0; k8 < 16; ++k8) {
      union { bf16x8 v; unsigned short u[8]; } h;
      h.v = *(const bf16x8*)(sAct + j * 136 + k8 * 8);
#pragma unroll
      for (int jj = 0; jj < 8; ++jj)
        a0 = fmaf(bf2f(h.u[jj]), sWo[o * 128 + k8 * 8 + jj], a0);
    }
    out[(b * 64 + j) * 5 + o] = a0 + b_o[o];
  }
}

extern "C" void kernel_launch(void* const* d_in, const int* in_sizes, int n_in,
                              void* d_out, int out_size, void* d_ws, size_t ws_size,
                              hipStream_t stream) {
  const float* x    = (const float*)d_in[0];
  const float* gso  = (const float*)d_in[1];
  const float* w_c1 = (const float*)d_in[2];
  const float* b_c1 = (const float*)d_in[3];
  const float* g_b1 = (const float*)d_in[4];
  const float* e_b1 = (const float*)d_in[5];
  const float* w_c2 = (const float*)d_in[6];
  const float* b_c2 = (const float*)d_in[7];
  const float* g_b2 = (const float*)d_in[8];
  const float* e_b2 = (const float*)d_in[9];
  const float* w_c3 = (const float*)d_in[10];
  const float* b_c3 = (const float*)d_in[11];
  const float* g_b3 = (const float*)d_in[12];
  const float* e_b3 = (const float*)d_in[13];
  const float* w_fc = (const float*)d_in[14];
  const float* b_fc = (const float*)d_in[15];
  const float* w_g1 = (const float*)d_in[16];
  const float* b_g1 = (const float*)d_in[17];
  const float* w_g2 = (const float*)d_in[18];
  const float* b_g2 = (const float*)d_in[19];
  const float* w_o  = (const float*)d_in[20];
  const float* b_o  = (const float*)d_in[21];
  float* out = (float*)d_out;
  char* ws = (char*)d_ws;

  // workspace layout (bytes) — NO ALIASING, total ~4.5 MB
  short* c3  = (short*)(ws + 0);         //  4,194,304
  short* B1  = (short*)(ws + 4194304);   //  4,096   (fragment order)
  short* B2  = (short*)(ws + 4198400);   //  36,864  (fragment order)
  short* B3  = (short*)(ws + 4235264);   //  147,456 (fragment order)
  short* Wfc = (short*)(ws + 4382720);   //  32,768
  short* Wg1 = (short*)(ws + 4415488);   //  32,768
  short* Wg2 = (short*)(ws + 4448256);   //  32,768

  pack_all<<<560, 256, 0, stream>>>(w_c1, w_c2, w_c3, w_fc, w_g1, w_g2,
                                    B1, B2, B3, Wfc, Wg1, Wg2);
  conv_all<<<1024, 256, 0, stream>>>(x, B1, B2, B3, b_c1, g_b1, e_b1,
                                     b_c2, g_b2, e_b2, b_c3, g_b3, e_b3, c3);
  fused_dense<<<256, 512, 0, stream>>>(c3, gso, Wfc, Wg1, Wg2, b_fc, b_g1,
                                       b_g2, w_o, b_o, out);
}